// Round 5
// baseline (501.664 us; speedup 1.0000x reference)
//
#include <hip/hip_runtime.h>
#include <stdint.h>

// out = (adj @ (X@W + b)) / rowsum(adj)
// B=8, N=4096, C_IN=C_OUT=512, all fp32 in/out. bf16 MFMA internally.
// ws: hT bf16 [8][512][4096] (32 MiB), Wt bf16 [512][512] after.

typedef __attribute__((ext_vector_type(4))) float  f32x4;
typedef __attribute__((ext_vector_type(8))) __bf16 bf16x8;
typedef __attribute__((ext_vector_type(4))) __bf16 bf16x4;

#define GLOAD_LDS16(gsrc, ldst)                                                           \
  __builtin_amdgcn_global_load_lds((const __attribute__((address_space(1))) void*)(gsrc), \
                                   (__attribute__((address_space(3))) void*)(ldst), 16, 0, 0)

#define BARRIER                                  \
  do {                                           \
    asm volatile("" ::: "memory");               \
    __builtin_amdgcn_s_barrier();                \
    asm volatile("" ::: "memory");               \
  } while (0)

// ---------------- K0: Wt[n][k] = bf16(W[k][n]), 512x512 ----------------
__global__ void __launch_bounds__(256) k_wt(const float* __restrict__ W,
                                            __bf16* __restrict__ Wt) {
  __shared__ __bf16 t[64][65];
  const int k0 = blockIdx.x * 64, n0 = blockIdx.y * 64;
  const int tid = threadIdx.x;
  const int r = tid >> 2, c4 = (tid & 3) * 16;
#pragma unroll
  for (int j = 0; j < 4; ++j) {
    f32x4 v = *reinterpret_cast<const f32x4*>(W + (size_t)(k0 + r) * 512 + n0 + c4 + j * 4);
#pragma unroll
    for (int q = 0; q < 4; ++q) t[c4 + j * 4 + q][r] = (__bf16)v[q];
  }
  __syncthreads();
#pragma unroll
  for (int j = 0; j < 4; ++j) {
    bf16x4 o;
#pragma unroll
    for (int q = 0; q < 4; ++q) o[q] = t[r][c4 + j * 4 + q];
    *reinterpret_cast<bf16x4*>(Wt + (size_t)(n0 + r) * 512 + k0 + c4 + j * 4) = o;
  }
}

// ---------------- K0b: zero the 8 per-batch sync counters (in out slabs) ----------
__global__ void k_zero(unsigned int* out) {
  if (threadIdx.x < 8) out[(size_t)threadIdx.x * 4096 * 512] = 0u;
}

// ---------------- K1: proj  h = X@W + b, stored transposed as hT[b][o][m] bf16 -----
__global__ void __launch_bounds__(256) k_proj(const float* __restrict__ X,
                                              const __bf16* __restrict__ Wt,
                                              const float* __restrict__ bias,
                                              __bf16* __restrict__ hT) {
  __shared__ __attribute__((aligned(16))) __bf16 Xs[128][72];
  __shared__ __attribute__((aligned(16))) __bf16 Ws[128][72];
  const int n0 = blockIdx.x * 128;
  const int m0 = blockIdx.y * 128;
  const int tid = threadIdx.x;
  const int lane = tid & 63, w = tid >> 6;
  const int wr = w >> 1, wc = w & 1;
  const int srow = tid >> 1, scb = (tid & 1) * 32;

  f32x4 acc[4][4] = {};

  for (int k0 = 0; k0 < 512; k0 += 64) {
    const float* xp = X + (size_t)(m0 + srow) * 512 + k0 + scb;
    f32x4 xv[8];
#pragma unroll
    for (int j = 0; j < 8; ++j) xv[j] = *reinterpret_cast<const f32x4*>(xp + j * 4);
#pragma unroll
    for (int q = 0; q < 4; ++q) {
      bf16x8 o;
#pragma unroll
      for (int e = 0; e < 8; ++e) { const int idx = q * 8 + e; o[e] = (__bf16)xv[idx >> 2][idx & 3]; }
      *reinterpret_cast<bf16x8*>(&Xs[srow][scb + q * 8]) = o;
    }
    const __bf16* wp = Wt + (size_t)(n0 + srow) * 512 + k0 + scb;
#pragma unroll
    for (int q = 0; q < 4; ++q)
      *reinterpret_cast<bf16x8*>(&Ws[srow][scb + q * 8]) =
          *reinterpret_cast<const bf16x8*>(wp + q * 8);
    __syncthreads();

    for (int kk = 0; kk < 64; kk += 32) {
      const int ko = kk + ((lane >> 4) << 3);
      bf16x8 a[4], bb[4];
#pragma unroll
      for (int i = 0; i < 4; ++i)
        a[i] = *reinterpret_cast<const bf16x8*>(&Xs[wr * 64 + i * 16 + (lane & 15)][ko]);
#pragma unroll
      for (int j = 0; j < 4; ++j)
        bb[j] = *reinterpret_cast<const bf16x8*>(&Ws[wc * 64 + j * 16 + (lane & 15)][ko]);
#pragma unroll
      for (int i = 0; i < 4; ++i)
#pragma unroll
        for (int j = 0; j < 4; ++j)
          acc[i][j] = __builtin_amdgcn_mfma_f32_16x16x32_bf16(a[i], bb[j], acc[i][j], 0, 0, 0);
    }
    __syncthreads();
  }

  float bj[4];
#pragma unroll
  for (int j = 0; j < 4; ++j) bj[j] = bias[n0 + wc * 64 + j * 16 + (lane & 15)];
  const int batch = m0 >> 12;
  const int mloc0 = (m0 & 4095) + wr * 64;
#pragma unroll
  for (int i = 0; i < 4; ++i) {
    const int m_in = mloc0 + i * 16 + ((lane >> 4) << 2);
#pragma unroll
    for (int j = 0; j < 4; ++j) {
      const int n = n0 + wc * 64 + j * 16 + (lane & 15);
      bf16x4 o;
#pragma unroll
      for (int r = 0; r < 4; ++r) o[r] = (__bf16)(acc[i][j][r] + bj[j]);
      *reinterpret_cast<bf16x4*>(hT + ((size_t)batch * 512 + n) * 4096 + m_in) = o;
    }
  }
}

// ---------------- K2: aggregation, counted-vmcnt pipeline + XCD lockstep -----------
// BM=128 x BN=512 (adj read once), BK=64, 8 waves (2x4), wave tile 64x128.
// As dbuf 2x16K + Hs dbuf 2x64K = 160 KiB, 1 block/CU. batch<->XCD swizzle.
// Every 8 K-tiles the 32 blocks of a batch rendezvous on a per-batch atomic
// counter -> hT super-tile (512 KiB) stays L2-resident, re-used 32x from L2
// instead of re-crossing the XCD fabric ingress. adj loads NT (single-use).
__global__ void __launch_bounds__(512, 2) k_agg(const float* __restrict__ adj,
                                                const __bf16* __restrict__ hT,
                                                float* __restrict__ out) {
  __shared__ __attribute__((aligned(16))) char lds[163840];
  char* As0 = lds;
  char* As1 = lds + 16384;
  char* Hs0 = lds + 32768;
  char* Hs1 = lds + 98304;

  const int bx = ((int)blockIdx.x & 7) * 32 + ((int)blockIdx.x >> 3);  // XCD x <-> batch x
  const int batch = bx >> 5;
  const int m0 = (bx & 31) * 128;
  const int tid = threadIdx.x;
  const int lane = tid & 63, w = tid >> 6;
  const int wr = w >> 2, wc = w & 3;  // wave tile: rows wr*64, cols wc*128

  const float*  adjb = adj + (size_t)batch * 4096 * 4096;
  const __bf16* hTb  = hT + (size_t)batch * 512 * 4096;
  float* outb = out + (size_t)batch * 4096 * 512;

  // A staging (verified): thread -> row tid>>2, 16 cols from (tid&3)*16, XOR-swizzled
  const int arow = tid >> 2;
  const int acb  = (tid & 3) * 16;
  const int aswz = (arow & 7) << 4;
  const int aw0  = arow * 128 + (((acb * 2) + 0) ^ aswz);
  const int aw1  = arow * 128 + (((acb * 2) + 16) ^ aswz);
  const float* adjrow = adjb + (size_t)(m0 + arow) * 4096 + acb;

  // Hs gload source pre-swizzle (verified)
  const int srcblk = (((lane & 7) ^ ((lane >> 3) & 7)) << 3);
  const int hrow_l = (lane >> 3);

  // fragment read swizzle
  const int koffbase = (lane >> 4) << 3;
  const int kswz = (lane & 7) << 4;

  f32x4 acc[4][8] = {};
  float pdeg = 0.f;
  f32x4 av[4];

  auto load_adj = [&](int k0) {  // non-temporal: stream-once, protect hT in L2
#pragma unroll
    for (int j = 0; j < 4; ++j)
      av[j] = __builtin_nontemporal_load(reinterpret_cast<const f32x4*>(adjrow + k0 + j * 4));
  };
  auto issue_hs = [&](int k0, char* Hn) {
#pragma unroll
    for (int q = 0; q < 8; ++q) {
      const int c = w * 8 + q;
      const __bf16* src = hTb + (size_t)(c * 8 + hrow_l) * 4096 + k0 + srcblk;
      GLOAD_LDS16(src, Hn + c * 1024);
    }
  };
  auto write_as = [&](char* An) {  // compiler inserts precise vmcnt for av
    bf16x8 o0, o1;
#pragma unroll
    for (int e = 0; e < 8; ++e) o0[e] = (__bf16)av[e >> 2][e & 3];
#pragma unroll
    for (int e = 0; e < 8; ++e) o1[e] = (__bf16)av[2 + (e >> 2)][e & 3];
    float s = 0.f;
#pragma unroll
    for (int e = 0; e < 16; ++e) s += av[e >> 2][e & 3];
    pdeg += s;
    *reinterpret_cast<bf16x8*>(An + aw0) = o0;
    *reinterpret_cast<bf16x8*>(An + aw1) = o1;
  };
  auto compute = [&](const char* Ac, const char* Hc) {
#pragma unroll
    for (int kk = 0; kk < 64; kk += 32) {
      const int ko2 = ((kk + koffbase) * 2) ^ kswz;
      bf16x8 a[4], bb[8];
#pragma unroll
      for (int i = 0; i < 4; ++i) {
        const int row = wr * 64 + i * 16 + (lane & 15);
        a[i] = *reinterpret_cast<const bf16x8*>(Ac + row * 128 + ko2);
      }
#pragma unroll
      for (int j = 0; j < 8; ++j) {
        const int orow = wc * 128 + j * 16 + (lane & 15);
        bb[j] = *reinterpret_cast<const bf16x8*>(Hc + orow * 128 + ko2);
      }
      asm volatile("s_waitcnt lgkmcnt(0)" ::: "memory");
      __builtin_amdgcn_sched_barrier(0);  // rule 18
      __builtin_amdgcn_s_setprio(1);
#pragma unroll
      for (int i = 0; i < 4; ++i)
#pragma unroll
        for (int j = 0; j < 8; ++j)
          acc[i][j] = __builtin_amdgcn_mfma_f32_16x16x32_bf16(a[i], bb[j], acc[i][j], 0, 0, 0);
      __builtin_amdgcn_s_setprio(0);
    }
  };
  // XCD-lockstep rendezvous: monotonic per-batch counter in the batch's out slab.
  // Cell is only overwritten (epilogue) after all 32 blocks passed the last barrier.
  auto super_sync = [&](unsigned int target) {
    if (tid == 0) {
      unsigned int* ctr = reinterpret_cast<unsigned int*>(outb);
      __hip_atomic_fetch_add(ctr, 1u, __ATOMIC_ACQ_REL, __HIP_MEMORY_SCOPE_AGENT);
      while (__hip_atomic_load(ctr, __ATOMIC_ACQUIRE, __HIP_MEMORY_SCOPE_AGENT) < target)
        __builtin_amdgcn_s_sleep(2);
    }
    __syncthreads();
  };

  // ---- prologue: stage tile 0 ----
  load_adj(0);
  issue_hs(0, Hs0);      // 8 gloads outstanding entering the loop
  write_as(As0);         // waits av (precise vmcnt), ds_writes pend

  // ---- main loop: 1 barrier per tile, counted vmcnt; lockstep every 8 tiles ----
  for (int t = 0; t < 63; ++t) {
    if ((t & 7) == 0 && t) super_sync((unsigned int)(t >> 3) * 32u);

    const int cur = t & 1;
    const char* Ac = cur ? As1 : As0;
    const char* Hc = cur ? Hs1 : Hs0;
    char* An = cur ? As0 : As1;
    char* Hn = cur ? Hs0 : Hs1;

    load_adj((t + 1) * 64);       // 4 VMEM
    issue_hs((t + 1) * 64, Hn);   // 8 VMEM  (outstanding: 8 old + 12 new)
    asm volatile("s_waitcnt vmcnt(12)" ::: "memory");  // drain ONLY prior tile's Hs gloads
    asm volatile("s_waitcnt lgkmcnt(0)" ::: "memory"); // own As(t) ds_writes drained
    BARRIER;                      // Hs[cur] + As[cur] published CU-wide
    compute(Ac, Hc);
    write_as(An);                 // av-wait precise; ds_writes drain at next lgkm(0)
  }

  // ---- last tile (t=63, buffers idx 1) ----
  asm volatile("s_waitcnt vmcnt(0)" ::: "memory");
  asm volatile("s_waitcnt lgkmcnt(0)" ::: "memory");
  BARRIER;
  compute(As1, Hs1);

  // ---- degree: reduce 4 col-quarter partials per row via shfl + reused LDS ----
  float d = pdeg;
  d += __shfl_xor(d, 1, 64);
  d += __shfl_xor(d, 2, 64);
  __syncthreads();  // all compute done; As region free for reuse
  if ((tid & 3) == 0) reinterpret_cast<float*>(lds)[arow] = d;
  __syncthreads();
  const float* degf = reinterpret_cast<const float*>(lds);

  // ---- epilogue: divide, NT store fp32 ----
#pragma unroll
  for (int i = 0; i < 4; ++i) {
    const int rbase = wr * 64 + i * 16 + ((lane >> 4) << 2);
    float rd[4];
#pragma unroll
    for (int r = 0; r < 4; ++r) rd[r] = 1.0f / degf[rbase + r];
#pragma unroll
    for (int j = 0; j < 8; ++j) {
      const int o = wc * 128 + j * 16 + (lane & 15);
#pragma unroll
      for (int r = 0; r < 4; ++r)
        __builtin_nontemporal_store(acc[i][j][r] * rd[r],
                                    &outb[(size_t)(m0 + rbase + r) * 512 + o]);
    }
  }
}

extern "C" void kernel_launch(void* const* d_in, const int* in_sizes, int n_in,
                              void* d_out, int out_size, void* d_ws, size_t ws_size,
                              hipStream_t stream) {
  (void)in_sizes; (void)n_in; (void)out_size; (void)ws_size;
  const float* X    = (const float*)d_in[0];  // [8,4096,512]
  const float* adj  = (const float*)d_in[1];  // [8,4096,4096]
  const float* W    = (const float*)d_in[2];  // [512,512]
  const float* bias = (const float*)d_in[3];  // [512]
  float* out = (float*)d_out;                 // [8,4096,512] fp32

  char* ws = (char*)d_ws;
  __bf16* hT = (__bf16*)ws;                                   // 32 MiB
  __bf16* Wt = (__bf16*)(ws + (size_t)32 * 1024 * 1024);      // 512 KiB

  k_zero<<<1, 64, 0, stream>>>((unsigned int*)d_out);
  k_wt<<<dim3(8, 8), 256, 0, stream>>>(W, Wt);
  k_proj<<<dim3(4, 256), 256, 0, stream>>>(X, Wt, bias, hT);
  k_agg<<<dim3(256), 512, 0, stream>>>(adj, hT, out);
}

// Round 6
// 244.620 us; speedup vs baseline: 2.0508x; 2.0508x over previous
//
#include <hip/hip_runtime.h>
#include <stdint.h>

// out = (adj @ (X@W + b)) / rowsum(adj)
// B=8, N=4096, C_IN=C_OUT=512, all fp32 in/out. bf16 MFMA internally.
// ws: hT bf16 [8][512][4096] (32 MiB), Wt bf16 [512][512] after.

typedef __attribute__((ext_vector_type(4))) float  f32x4;
typedef __attribute__((ext_vector_type(8))) __bf16 bf16x8;
typedef __attribute__((ext_vector_type(4))) __bf16 bf16x4;

#define GLOAD_LDS16(gsrc, ldst)                                                           \
  __builtin_amdgcn_global_load_lds((const __attribute__((address_space(1))) void*)(gsrc), \
                                   (__attribute__((address_space(3))) void*)(ldst), 16, 0, 0)

#define BARRIER                                  \
  do {                                           \
    asm volatile("" ::: "memory");               \
    __builtin_amdgcn_s_barrier();                \
    asm volatile("" ::: "memory");               \
  } while (0)

// ---------------- K0: Wt[n][k] = bf16(W[k][n]), 512x512 ----------------
__global__ void __launch_bounds__(256) k_wt(const float* __restrict__ W,
                                            __bf16* __restrict__ Wt) {
  __shared__ __bf16 t[64][65];
  const int k0 = blockIdx.x * 64, n0 = blockIdx.y * 64;
  const int tid = threadIdx.x;
  const int r = tid >> 2, c4 = (tid & 3) * 16;
#pragma unroll
  for (int j = 0; j < 4; ++j) {
    f32x4 v = *reinterpret_cast<const f32x4*>(W + (size_t)(k0 + r) * 512 + n0 + c4 + j * 4);
#pragma unroll
    for (int q = 0; q < 4; ++q) t[c4 + j * 4 + q][r] = (__bf16)v[q];
  }
  __syncthreads();
#pragma unroll
  for (int j = 0; j < 4; ++j) {
    bf16x4 o;
#pragma unroll
    for (int q = 0; q < 4; ++q) o[q] = t[r][c4 + j * 4 + q];
    *reinterpret_cast<bf16x4*>(Wt + (size_t)(n0 + r) * 512 + k0 + c4 + j * 4) = o;
  }
}

// ---------------- K1: proj  h = X@W + b, stored transposed as hT[b][o][m] bf16 -----
__global__ void __launch_bounds__(256) k_proj(const float* __restrict__ X,
                                              const __bf16* __restrict__ Wt,
                                              const float* __restrict__ bias,
                                              __bf16* __restrict__ hT) {
  __shared__ __attribute__((aligned(16))) __bf16 Xs[128][72];
  __shared__ __attribute__((aligned(16))) __bf16 Ws[128][72];
  const int n0 = blockIdx.x * 128;
  const int m0 = blockIdx.y * 128;
  const int tid = threadIdx.x;
  const int lane = tid & 63, w = tid >> 6;
  const int wr = w >> 1, wc = w & 1;
  const int srow = tid >> 1, scb = (tid & 1) * 32;

  f32x4 acc[4][4] = {};

  for (int k0 = 0; k0 < 512; k0 += 64) {
    const float* xp = X + (size_t)(m0 + srow) * 512 + k0 + scb;
    f32x4 xv[8];
#pragma unroll
    for (int j = 0; j < 8; ++j) xv[j] = *reinterpret_cast<const f32x4*>(xp + j * 4);
#pragma unroll
    for (int q = 0; q < 4; ++q) {
      bf16x8 o;
#pragma unroll
      for (int e = 0; e < 8; ++e) { const int idx = q * 8 + e; o[e] = (__bf16)xv[idx >> 2][idx & 3]; }
      *reinterpret_cast<bf16x8*>(&Xs[srow][scb + q * 8]) = o;
    }
    const __bf16* wp = Wt + (size_t)(n0 + srow) * 512 + k0 + scb;
#pragma unroll
    for (int q = 0; q < 4; ++q)
      *reinterpret_cast<bf16x8*>(&Ws[srow][scb + q * 8]) =
          *reinterpret_cast<const bf16x8*>(wp + q * 8);
    __syncthreads();

    for (int kk = 0; kk < 64; kk += 32) {
      const int ko = kk + ((lane >> 4) << 3);
      bf16x8 a[4], bb[4];
#pragma unroll
      for (int i = 0; i < 4; ++i)
        a[i] = *reinterpret_cast<const bf16x8*>(&Xs[wr * 64 + i * 16 + (lane & 15)][ko]);
#pragma unroll
      for (int j = 0; j < 4; ++j)
        bb[j] = *reinterpret_cast<const bf16x8*>(&Ws[wc * 64 + j * 16 + (lane & 15)][ko]);
#pragma unroll
      for (int i = 0; i < 4; ++i)
#pragma unroll
        for (int j = 0; j < 4; ++j)
          acc[i][j] = __builtin_amdgcn_mfma_f32_16x16x32_bf16(a[i], bb[j], acc[i][j], 0, 0, 0);
    }
    __syncthreads();
  }

  float bj[4];
#pragma unroll
  for (int j = 0; j < 4; ++j) bj[j] = bias[n0 + wc * 64 + j * 16 + (lane & 15)];
  const int batch = m0 >> 12;
  const int mloc0 = (m0 & 4095) + wr * 64;
#pragma unroll
  for (int i = 0; i < 4; ++i) {
    const int m_in = mloc0 + i * 16 + ((lane >> 4) << 2);
#pragma unroll
    for (int j = 0; j < 4; ++j) {
      const int n = n0 + wc * 64 + j * 16 + (lane & 15);
      bf16x4 o;
#pragma unroll
      for (int r = 0; r < 4; ++r) o[r] = (__bf16)(acc[i][j][r] + bj[j]);
      *reinterpret_cast<bf16x4*>(hT + ((size_t)batch * 512 + n) * 4096 + m_in) = o;
    }
  }
}

// ---------------- K2: aggregation, 16-wave counted-vmcnt pipeline ------------------
// BM=128 x BN=512 (adj read once), BK=64, 16 waves (2x8), wave tile 64x64,
// acc[4][4]=64 VGPR. As dbuf 2x16K + Hs dbuf 2x64K = 160 KiB, 1 block/CU but
// 16 waves/CU (was 8) -> 4 waves/SIMD latency hiding (R5 counters: latency-bound
// at 22% occupancy, all pipes idle; FETCH shows hT is L2/L3-served, not HBM).
// Per tile: issue 6 VMEM (t+1) -> vmcnt(6) [drains only prior Hs gloads] ->
// lgkm(0) -> barrier -> compute -> write_as (compiler-precise vmcnt for av).
__global__ void __launch_bounds__(1024, 4) k_agg(const float* __restrict__ adj,
                                                 const __bf16* __restrict__ hT,
                                                 float* __restrict__ out) {
  __shared__ __attribute__((aligned(16))) char lds[163840];
  char* As0 = lds;
  char* As1 = lds + 16384;
  char* Hs0 = lds + 32768;
  char* Hs1 = lds + 98304;

  const int bx = ((int)blockIdx.x & 7) * 32 + ((int)blockIdx.x >> 3);  // XCD x <-> batch x
  const int batch = bx >> 5;
  const int m0 = (bx & 31) * 128;
  const int tid = threadIdx.x;
  const int lane = tid & 63, w = tid >> 6;
  const int wr = w >> 3, wc = w & 7;  // wave tile: rows wr*64, cols wc*64

  const float*  adjb = adj + (size_t)batch * 4096 * 4096;
  const __bf16* hTb  = hT + (size_t)batch * 512 * 4096;
  float* outb = out + (size_t)batch * 4096 * 512;

  // A staging: thread -> row tid>>3, 8 cols from (tid&7)*8, XOR-swizzled write
  const int arow = tid >> 3;
  const int acb  = (tid & 7) * 8;
  const int aw   = arow * 128 + (((acb * 2)) ^ ((arow & 7) << 4));
  const float* adjrow = adjb + (size_t)(m0 + arow) * 4096 + acb;

  // Hs gload source pre-swizzle (verified): lane writes 16B block (l&7) of row l>>3
  const int srcblk = (((lane & 7) ^ ((lane >> 3) & 7)) << 3);
  const int hrow_l = (lane >> 3);

  // fragment read swizzle
  const int koffbase = (lane >> 4) << 3;
  const int kswz = (lane & 7) << 4;

  f32x4 acc[4][4] = {};
  float pdeg = 0.f;
  f32x4 av[2];

  auto load_adj = [&](int k0) {  // non-temporal: single-use, protect hT L2 residency
    av[0] = __builtin_nontemporal_load(reinterpret_cast<const f32x4*>(adjrow + k0));
    av[1] = __builtin_nontemporal_load(reinterpret_cast<const f32x4*>(adjrow + k0 + 4));
  };
  auto issue_hs = [&](int k0, char* Hn) {  // 4 chunks of 1 KiB per wave (64 chunks)
#pragma unroll
    for (int q = 0; q < 4; ++q) {
      const int c = w * 4 + q;
      const __bf16* src = hTb + (size_t)(c * 8 + hrow_l) * 4096 + k0 + srcblk;
      GLOAD_LDS16(src, Hn + c * 1024);
    }
  };
  auto write_as = [&](char* An) {  // compiler inserts precise vmcnt for av
    bf16x8 o0;
#pragma unroll
    for (int e = 0; e < 8; ++e) o0[e] = (__bf16)av[e >> 2][e & 3];
    float s = 0.f;
#pragma unroll
    for (int e = 0; e < 8; ++e) s += av[e >> 2][e & 3];
    pdeg += s;
    *reinterpret_cast<bf16x8*>(An + aw) = o0;
  };
  auto compute = [&](const char* Ac, const char* Hc) {
#pragma unroll
    for (int kk = 0; kk < 64; kk += 32) {
      const int ko2 = ((kk + koffbase) * 2) ^ kswz;
      bf16x8 a[4], bb[4];
#pragma unroll
      for (int i = 0; i < 4; ++i) {
        const int row = wr * 64 + i * 16 + (lane & 15);
        a[i] = *reinterpret_cast<const bf16x8*>(Ac + row * 128 + ko2);
      }
#pragma unroll
      for (int j = 0; j < 4; ++j) {
        const int orow = wc * 64 + j * 16 + (lane & 15);
        bb[j] = *reinterpret_cast<const bf16x8*>(Hc + orow * 128 + ko2);
      }
      asm volatile("s_waitcnt lgkmcnt(0)" ::: "memory");
      __builtin_amdgcn_sched_barrier(0);  // rule 18
      __builtin_amdgcn_s_setprio(1);
#pragma unroll
      for (int i = 0; i < 4; ++i)
#pragma unroll
        for (int j = 0; j < 4; ++j)
          acc[i][j] = __builtin_amdgcn_mfma_f32_16x16x32_bf16(a[i], bb[j], acc[i][j], 0, 0, 0);
      __builtin_amdgcn_s_setprio(0);
    }
  };

  // ---- prologue: stage tile 0 ----
  load_adj(0);
  issue_hs(0, Hs0);      // 4 gloads outstanding entering the loop
  write_as(As0);         // waits av (precise vmcnt), ds_write pends

  // ---- main loop: 1 barrier per tile, counted vmcnt ----
  for (int t = 0; t < 63; ++t) {
    const int cur = t & 1;
    const char* Ac = cur ? As1 : As0;
    const char* Hc = cur ? Hs1 : Hs0;
    char* An = cur ? As0 : As1;
    char* Hn = cur ? Hs0 : Hs1;

    load_adj((t + 1) * 64);       // 2 VMEM
    issue_hs((t + 1) * 64, Hn);   // 4 VMEM  (outstanding: 4 old + 6 new)
    asm volatile("s_waitcnt vmcnt(6)" ::: "memory");   // drain ONLY prior tile's Hs gloads
    asm volatile("s_waitcnt lgkmcnt(0)" ::: "memory"); // own As(t) ds_write drained
    BARRIER;                      // Hs[cur] + As[cur] published CU-wide
    compute(Ac, Hc);
    write_as(An);                 // av-wait precise; ds_write drains at next lgkm(0)
  }

  // ---- last tile (t=63, buffers idx 1) ----
  asm volatile("s_waitcnt vmcnt(0)" ::: "memory");
  asm volatile("s_waitcnt lgkmcnt(0)" ::: "memory");
  BARRIER;
  compute(As1, Hs1);

  // ---- degree: 8 partials per row (threads tid>>3 equal), shfl + reused LDS ----
  float d = pdeg;
  d += __shfl_xor(d, 1, 64);
  d += __shfl_xor(d, 2, 64);
  d += __shfl_xor(d, 4, 64);
  __syncthreads();  // all compute done; As region free for reuse
  if ((tid & 7) == 0) reinterpret_cast<float*>(lds)[arow] = d;
  __syncthreads();
  const float* degf = reinterpret_cast<const float*>(lds);

  // ---- epilogue: divide, NT store fp32 ----
#pragma unroll
  for (int i = 0; i < 4; ++i) {
    const int rbase = wr * 64 + i * 16 + ((lane >> 4) << 2);
    float rd[4];
#pragma unroll
    for (int r = 0; r < 4; ++r) rd[r] = 1.0f / degf[rbase + r];
#pragma unroll
    for (int j = 0; j < 4; ++j) {
      const int o = wc * 64 + j * 16 + (lane & 15);
#pragma unroll
      for (int r = 0; r < 4; ++r)
        __builtin_nontemporal_store(acc[i][j][r] * rd[r],
                                    &outb[(size_t)(m0 + rbase + r) * 512 + o]);
    }
  }
}

extern "C" void kernel_launch(void* const* d_in, const int* in_sizes, int n_in,
                              void* d_out, int out_size, void* d_ws, size_t ws_size,
                              hipStream_t stream) {
  (void)in_sizes; (void)n_in; (void)out_size; (void)ws_size;
  const float* X    = (const float*)d_in[0];  // [8,4096,512]
  const float* adj  = (const float*)d_in[1];  // [8,4096,4096]
  const float* W    = (const float*)d_in[2];  // [512,512]
  const float* bias = (const float*)d_in[3];  // [512]
  float* out = (float*)d_out;                 // [8,4096,512] fp32

  char* ws = (char*)d_ws;
  __bf16* hT = (__bf16*)ws;                                   // 32 MiB
  __bf16* Wt = (__bf16*)(ws + (size_t)32 * 1024 * 1024);      // 512 KiB

  k_wt<<<dim3(8, 8), 256, 0, stream>>>(W, Wt);
  k_proj<<<dim3(4, 256), 256, 0, stream>>>(X, Wt, bias, hT);
  k_agg<<<dim3(256), 1024, 0, stream>>>(adj, hT, out);
}

// Round 8
// 236.056 us; speedup vs baseline: 2.1252x; 1.0363x over previous
//
#include <hip/hip_runtime.h>
#include <stdint.h>

// out = (adj @ (X@W + b)) / rowsum(adj)
// B=8, N=4096, C_IN=C_OUT=512, all fp32 in/out. bf16 MFMA internally.
// ws: hT bf16 [8][512][4096] (32 MiB), Wt bf16 [512][512] after.

typedef __attribute__((ext_vector_type(4))) float  f32x4;
typedef __attribute__((ext_vector_type(8))) __bf16 bf16x8;
typedef __attribute__((ext_vector_type(4))) __bf16 bf16x4;

#define GLOAD_LDS16(gsrc, ldst)                                                           \
  __builtin_amdgcn_global_load_lds((const __attribute__((address_space(1))) void*)(gsrc), \
                                   (__attribute__((address_space(3))) void*)(ldst), 16, 0, 0)

#define BARRIER                                  \
  do {                                           \
    asm volatile("" ::: "memory");               \
    __builtin_amdgcn_s_barrier();                \
    asm volatile("" ::: "memory");               \
  } while (0)

// ---------------- K0: Wt[n][k] = bf16(W[k][n]), 512x512 ----------------
__global__ void __launch_bounds__(256) k_wt(const float* __restrict__ W,
                                            __bf16* __restrict__ Wt) {
  __shared__ __bf16 t[64][65];
  const int k0 = blockIdx.x * 64, n0 = blockIdx.y * 64;
  const int tid = threadIdx.x;
  const int r = tid >> 2, c4 = (tid & 3) * 16;
#pragma unroll
  for (int j = 0; j < 4; ++j) {
    f32x4 v = *reinterpret_cast<const f32x4*>(W + (size_t)(k0 + r) * 512 + n0 + c4 + j * 4);
#pragma unroll
    for (int q = 0; q < 4; ++q) t[c4 + j * 4 + q][r] = (__bf16)v[q];
  }
  __syncthreads();
#pragma unroll
  for (int j = 0; j < 4; ++j) {
    bf16x4 o;
#pragma unroll
    for (int q = 0; q < 4; ++q) o[q] = t[r][c4 + j * 4 + q];
    *reinterpret_cast<bf16x4*>(Wt + (size_t)(n0 + r) * 512 + k0 + c4 + j * 4) = o;
  }
}

// ---------------- K1: proj  h = X@W + b, stored transposed as hT[b][o][m] bf16 -----
__global__ void __launch_bounds__(256) k_proj(const float* __restrict__ X,
                                              const __bf16* __restrict__ Wt,
                                              const float* __restrict__ bias,
                                              __bf16* __restrict__ hT) {
  __shared__ __attribute__((aligned(16))) __bf16 Xs[128][72];
  __shared__ __attribute__((aligned(16))) __bf16 Ws[128][72];
  const int n0 = blockIdx.x * 128;
  const int m0 = blockIdx.y * 128;
  const int tid = threadIdx.x;
  const int lane = tid & 63, w = tid >> 6;
  const int wr = w >> 1, wc = w & 1;
  const int srow = tid >> 1, scb = (tid & 1) * 32;

  f32x4 acc[4][4] = {};

  for (int k0 = 0; k0 < 512; k0 += 64) {
    const float* xp = X + (size_t)(m0 + srow) * 512 + k0 + scb;
    f32x4 xv[8];
#pragma unroll
    for (int j = 0; j < 8; ++j) xv[j] = *reinterpret_cast<const f32x4*>(xp + j * 4);
#pragma unroll
    for (int q = 0; q < 4; ++q) {
      bf16x8 o;
#pragma unroll
      for (int e = 0; e < 8; ++e) { const int idx = q * 8 + e; o[e] = (__bf16)xv[idx >> 2][idx & 3]; }
      *reinterpret_cast<bf16x8*>(&Xs[srow][scb + q * 8]) = o;
    }
    const __bf16* wp = Wt + (size_t)(n0 + srow) * 512 + k0 + scb;
#pragma unroll
    for (int q = 0; q < 4; ++q)
      *reinterpret_cast<bf16x8*>(&Ws[srow][scb + q * 8]) =
          *reinterpret_cast<const bf16x8*>(wp + q * 8);
    __syncthreads();

    for (int kk = 0; kk < 64; kk += 32) {
      const int ko = kk + ((lane >> 4) << 3);
      bf16x8 a[4], bb[4];
#pragma unroll
      for (int i = 0; i < 4; ++i)
        a[i] = *reinterpret_cast<const bf16x8*>(&Xs[wr * 64 + i * 16 + (lane & 15)][ko]);
#pragma unroll
      for (int j = 0; j < 4; ++j)
        bb[j] = *reinterpret_cast<const bf16x8*>(&Ws[wc * 64 + j * 16 + (lane & 15)][ko]);
#pragma unroll
      for (int i = 0; i < 4; ++i)
#pragma unroll
        for (int j = 0; j < 4; ++j)
          acc[i][j] = __builtin_amdgcn_mfma_f32_16x16x32_bf16(a[i], bb[j], acc[i][j], 0, 0, 0);
    }
    __syncthreads();
  }

  float bj[4];
#pragma unroll
  for (int j = 0; j < 4; ++j) bj[j] = bias[n0 + wc * 64 + j * 16 + (lane & 15)];
  const int batch = m0 >> 12;
  const int mloc0 = (m0 & 4095) + wr * 64;
#pragma unroll
  for (int i = 0; i < 4; ++i) {
    const int m_in = mloc0 + i * 16 + ((lane >> 4) << 2);
#pragma unroll
    for (int j = 0; j < 4; ++j) {
      const int n = n0 + wc * 64 + j * 16 + (lane & 15);
      bf16x4 o;
#pragma unroll
      for (int r = 0; r < 4; ++r) o[r] = (__bf16)(acc[i][j][r] + bj[j]);
      *reinterpret_cast<bf16x4*>(hT + ((size_t)batch * 512 + n) * 4096 + m_in) = o;
    }
  }
}

// ---------------- K2: aggregation, 16-wave race-free single-barrier pipeline -------
// BM=128 x BN=512 (adj read once), BK=64, 16 waves (2x8), wave tile 64x64.
// As dbuf 2x16K + Hs dbuf 2x64K = 160 KiB, 16 waves/CU (VGPR<=128 band).
// WAR-safe ordering (R7 lesson): prefetch into buffers [1-cur] is issued AFTER
// the barrier (their readers all finished at that barrier). Per tile:
// BARRIER -> issue adj+Hs(t+1) -> compute(cur) -> write_as -> vmcnt(0) [only
// the 4 Hs gloads remain, issued a full compute-phase earlier] -> lgkm(0) -> BARRIER.
// Inside compute: no manual drains/setprio -- compiler emits counted lgkmcnt
// and pipelines ds_reads under MFMAs.
__global__ void __launch_bounds__(1024, 4) k_agg(const float* __restrict__ adj,
                                                 const __bf16* __restrict__ hT,
                                                 float* __restrict__ out) {
  __shared__ __attribute__((aligned(16))) char lds[163840];
  char* As0 = lds;
  char* As1 = lds + 16384;
  char* Hs0 = lds + 32768;
  char* Hs1 = lds + 98304;

  const int bx = ((int)blockIdx.x & 7) * 32 + ((int)blockIdx.x >> 3);  // XCD x <-> batch x
  const int batch = bx >> 5;
  const int m0 = (bx & 31) * 128;
  const int tid = threadIdx.x;
  const int lane = tid & 63, w = tid >> 6;
  const int wr = w >> 3, wc = w & 7;  // wave tile: rows wr*64, cols wc*64

  const float*  adjb = adj + (size_t)batch * 4096 * 4096;
  const __bf16* hTb  = hT + (size_t)batch * 512 * 4096;
  float* outb = out + (size_t)batch * 4096 * 512;

  // A staging: thread -> row tid>>3, 8 cols from (tid&7)*8, XOR-swizzled write
  const int arow = tid >> 3;
  const int acb  = (tid & 7) * 8;
  const int aw   = arow * 128 + (((acb * 2)) ^ ((arow & 7) << 4));
  const float* adjrow = adjb + (size_t)(m0 + arow) * 4096 + acb;

  // Hs gload source pre-swizzle (verified): lane writes 16B block (l&7) of row l>>3
  const int srcblk = (((lane & 7) ^ ((lane >> 3) & 7)) << 3);
  const int hrow_l = (lane >> 3);

  // fragment read swizzle
  const int koffbase = (lane >> 4) << 3;
  const int kswz = (lane & 7) << 4;

  f32x4 acc[4][4] = {};
  float pdeg = 0.f;
  f32x4 av[2];

  auto load_adj = [&](int k0) {  // non-temporal: single-use, protect hT L2 residency
    av[0] = __builtin_nontemporal_load(reinterpret_cast<const f32x4*>(adjrow + k0));
    av[1] = __builtin_nontemporal_load(reinterpret_cast<const f32x4*>(adjrow + k0 + 4));
  };
  auto issue_hs = [&](int k0, char* Hn) {  // 4 chunks of 1 KiB per wave (64 chunks)
#pragma unroll
    for (int q = 0; q < 4; ++q) {
      const int c = w * 4 + q;
      const __bf16* src = hTb + (size_t)(c * 8 + hrow_l) * 4096 + k0 + srcblk;
      GLOAD_LDS16(src, Hn + c * 1024);
    }
  };
  auto write_as = [&](char* An) {  // compiler inserts precise vmcnt for av
    bf16x8 o0;
#pragma unroll
    for (int e = 0; e < 8; ++e) o0[e] = (__bf16)av[e >> 2][e & 3];
    float s = 0.f;
#pragma unroll
    for (int e = 0; e < 8; ++e) s += av[e >> 2][e & 3];
    pdeg += s;
    *reinterpret_cast<bf16x8*>(An + aw) = o0;
  };
  auto compute = [&](const char* Ac, const char* Hc) {
#pragma unroll
    for (int kk = 0; kk < 64; kk += 32) {
      const int ko2 = ((kk + koffbase) * 2) ^ kswz;
      bf16x8 a[4], bb[4];
#pragma unroll
      for (int i = 0; i < 4; ++i) {
        const int row = wr * 64 + i * 16 + (lane & 15);
        a[i] = *reinterpret_cast<const bf16x8*>(Ac + row * 128 + ko2);
      }
#pragma unroll
      for (int j = 0; j < 4; ++j) {
        const int orow = wc * 64 + j * 16 + (lane & 15);
        bb[j] = *reinterpret_cast<const bf16x8*>(Hc + orow * 128 + ko2);
      }
#pragma unroll
      for (int i = 0; i < 4; ++i)
#pragma unroll
        for (int j = 0; j < 4; ++j)
          acc[i][j] = __builtin_amdgcn_mfma_f32_16x16x32_bf16(a[i], bb[j], acc[i][j], 0, 0, 0);
    }
  };

  // ---- prologue: stage tile 0 fully, publish ----
  load_adj(0);
  issue_hs(0, Hs0);
  write_as(As0);
  asm volatile("s_waitcnt vmcnt(0)" ::: "memory");
  asm volatile("s_waitcnt lgkmcnt(0)" ::: "memory");
  BARRIER;

  // ---- main loop: 1 barrier per tile, prefetch issued AFTER the barrier ----
  for (int t = 0; t < 63; ++t) {
    const int cur = t & 1;
    const char* Ac = cur ? As1 : As0;
    const char* Hc = cur ? Hs1 : Hs0;
    char* An = cur ? As0 : As1;
    char* Hn = cur ? Hs0 : Hs1;

    load_adj((t + 1) * 64);       // register loads: no LDS hazard
    issue_hs((t + 1) * 64, Hn);   // WAR-safe: Hn's readers finished at last barrier
    compute(Ac, Hc);              // overlaps the 6 in-flight VMEM
    write_as(An);                 // WAR-safe same way; waits adj (precise vmcnt)
    asm volatile("s_waitcnt vmcnt(0)" ::: "memory");   // only 4 Hs gloads left; short wait
    asm volatile("s_waitcnt lgkmcnt(0)" ::: "memory"); // own ds_write drained
    BARRIER;                      // tile t+1 buffers published
  }

  // ---- last tile (t=63, buffers idx 1) ----
  compute(As1, Hs1);

  // ---- degree: 8 partials per row (threads tid>>3 equal), shfl + reused LDS ----
  float d = pdeg;
  d += __shfl_xor(d, 1, 64);
  d += __shfl_xor(d, 2, 64);
  d += __shfl_xor(d, 4, 64);
  __syncthreads();  // all compute done; As region free for reuse
  if ((tid & 7) == 0) reinterpret_cast<float*>(lds)[arow] = d;
  __syncthreads();
  const float* degf = reinterpret_cast<const float*>(lds);

  // ---- epilogue: divide, NT store fp32 ----
#pragma unroll
  for (int i = 0; i < 4; ++i) {
    const int rbase = wr * 64 + i * 16 + ((lane >> 4) << 2);
    float rd[4];
#pragma unroll
    for (int r = 0; r < 4; ++r) rd[r] = 1.0f / degf[rbase + r];
#pragma unroll
    for (int j = 0; j < 4; ++j) {
      const int o = wc * 64 + j * 16 + (lane & 15);
#pragma unroll
      for (int r = 0; r < 4; ++r)
        __builtin_nontemporal_store(acc[i][j][r] * rd[r],
                                    &outb[(size_t)(m0 + rbase + r) * 512 + o]);
    }
  }
}

extern "C" void kernel_launch(void* const* d_in, const int* in_sizes, int n_in,
                              void* d_out, int out_size, void* d_ws, size_t ws_size,
                              hipStream_t stream) {
  (void)in_sizes; (void)n_in; (void)out_size; (void)ws_size;
  const float* X    = (const float*)d_in[0];  // [8,4096,512]
  const float* adj  = (const float*)d_in[1];  // [8,4096,4096]
  const float* W    = (const float*)d_in[2];  // [512,512]
  const float* bias = (const float*)d_in[3];  // [512]
  float* out = (float*)d_out;                 // [8,4096,512] fp32

  char* ws = (char*)d_ws;
  __bf16* hT = (__bf16*)ws;                                   // 32 MiB
  __bf16* Wt = (__bf16*)(ws + (size_t)32 * 1024 * 1024);      // 512 KiB

  k_wt<<<dim3(8, 8), 256, 0, stream>>>(W, Wt);
  k_proj<<<dim3(4, 256), 256, 0, stream>>>(X, Wt, bias, hT);
  k_agg<<<dim3(256), 1024, 0, stream>>>(adj, hT, out);
}